// Round 1
// baseline (208.772 us; speedup 1.0000x reference)
//
#include <hip/hip_runtime.h>

// ---------------------------------------------------------------------------
// Complex Daubechies wavelet pyramid, 6 levels, circular boundary, 6 taps.
// Layout: d_out = [B, C, 2, H, W] fp32 (plane 0 = real, plane 1 = imag).
// Each level's kernel fuses: column pass (H) -> row pass (W) -> 4 bands,
// and additionally emits the LL band compactly into d_ws as the next level's
// input (reference does res[..., :h, :w].copy() -- this replaces the copy).
// ---------------------------------------------------------------------------

#define SQ2 0.7071067811865476

// Filter taps (pre-scaled by 1/sqrt(2)), computed in double, cast to float.
__device__ __constant__ float c_LOR[6] = {
    (float)(-0.0662912607 * SQ2), (float)( 0.1104854346 * SQ2),
    (float)( 0.6629126074 * SQ2), (float)( 0.6629126074 * SQ2),
    (float)( 0.1104854346 * SQ2), (float)(-0.0662912607 * SQ2)};
__device__ __constant__ float c_LOI[6] = {
    (float)(-0.0855816496 * SQ2), (float)(-0.0855816496 * SQ2),
    (float)( 0.1711632992 * SQ2), (float)( 0.1711632992 * SQ2),
    (float)(-0.0855816496 * SQ2), (float)(-0.0855816496 * SQ2)};
__device__ __constant__ float c_HIR[6] = {
    (float)(-0.0662912607 * SQ2), (float)(-0.1104854346 * SQ2),
    (float)( 0.6629126074 * SQ2), (float)(-0.6629126074 * SQ2),
    (float)( 0.1104854346 * SQ2), (float)( 0.0662912607 * SQ2)};
__device__ __constant__ float c_HII[6] = {
    (float)( 0.0855816496 * SQ2), (float)(-0.0855816496 * SQ2),
    (float)(-0.1711632992 * SQ2), (float)( 0.1711632992 * SQ2),
    (float)( 0.0855816496 * SQ2), (float)(-0.0855816496 * SQ2)};

constexpr int TI = 16;              // output band tile rows
constexpr int TJ = 16;              // output band tile cols
constexpr int RROWS = 2 * TI + 5;   // 37 input rows needed
constexpr int RCOLS = 2 * TJ + 5;   // 37 input cols needed
constexpr int LDW = 41;             // padded LDS stride (odd -> conflict-free-ish)

// inR/inI: compact [B*C, h, w] planes (inI unused when !HAS_IMAG).
// out: base of [B, C, 2, H, W]. llR/llI: compact [B*C, h/2, w/2] (next level).
template <bool HAS_IMAG, bool WRITE_LL>
__global__ __launch_bounds__(256) void dwt_level_kernel(
    const float* __restrict__ inR, const float* __restrict__ inI,
    float* __restrict__ out, float* __restrict__ llR, float* __restrict__ llI,
    int h, int w, int tilesPerRow, int tilesPerPlane, int HW, int W0) {
  __shared__ float sR[RROWS][LDW];
  __shared__ float sI[RROWS][LDW];
  __shared__ float yloR[TI][LDW];
  __shared__ float yloI[TI][LDW];
  __shared__ float yhiR[TI][LDW];
  __shared__ float yhiI[TI][LDW];

  const int tid = threadIdx.x;
  const int bid = blockIdx.x;
  const int plane = bid / tilesPerPlane;
  const int trem = bid - plane * tilesPerPlane;
  const int ti = trem / tilesPerRow;
  const int tj = trem - ti * tilesPerRow;

  const int hm = h - 1, wm = w - 1;
  const int i0 = ti * TI, j0 = tj * TJ;
  const float* pinR = inR + (size_t)plane * h * w;
  const float* pinI = HAS_IMAG ? (inI + (size_t)plane * h * w) : nullptr;

  // ---- stage 1: load (2*TI+5) x (2*TJ+5) input tile, circular wrap ----
  for (int idx = tid; idx < RROWS * RCOLS; idx += 256) {
    const int rr = idx / RCOLS;
    const int cc = idx - rr * RCOLS;
    const int gr = (2 * i0 - 3 + rr + h) & hm;
    const int gc = (2 * j0 - 3 + cc + w) & wm;
    sR[rr][cc] = pinR[gr * w + gc];
    if (HAS_IMAG) sI[rr][cc] = pinI[gr * w + gc];
  }
  __syncthreads();

  // ---- stage 2: column pass (along H) -> low/high complex rows ----
  for (int idx = tid; idx < TI * RCOLS; idx += 256) {
    const int i = idx / RCOLS;
    const int x = idx - i * RCOLS;
    float lr = 0.f, li = 0.f, hr = 0.f, hi = 0.f;
#pragma unroll
    for (int t = 0; t < 6; ++t) {
      const float xr = sR[2 * i + t][x];
      lr += c_LOR[t] * xr;
      li += c_LOI[t] * xr;
      hr += c_HIR[t] * xr;
      hi += c_HII[t] * xr;
      if (HAS_IMAG) {
        const float xi = sI[2 * i + t][x];
        lr -= c_LOI[t] * xi;
        li += c_LOR[t] * xi;
        hr -= c_HII[t] * xi;
        hi += c_HIR[t] * xi;
      }
    }
    yloR[i][x] = lr;
    yloI[i][x] = li;
    yhiR[i][x] = hr;
    yhiI[i][x] = hi;
  }
  __syncthreads();

  // ---- stage 3: row pass (along W), one thread per (i,j) output ----
  const int i = tid >> 4;
  const int j = tid & 15;
  float llr = 0.f, lli = 0.f, lhr = 0.f, lhi = 0.f;
  float hlr = 0.f, hli = 0.f, hhr = 0.f, hhi = 0.f;
#pragma unroll
  for (int t = 0; t < 6; ++t) {
    const float ar = yloR[i][2 * j + t];
    const float ai = yloI[i][2 * j + t];
    llr += c_LOR[t] * ar - c_LOI[t] * ai;
    lli += c_LOI[t] * ar + c_LOR[t] * ai;
    lhr += c_HIR[t] * ar - c_HII[t] * ai;
    lhi += c_HII[t] * ar + c_HIR[t] * ai;
    const float br = yhiR[i][2 * j + t];
    const float bi = yhiI[i][2 * j + t];
    hlr += c_LOR[t] * br - c_LOI[t] * bi;
    hli += c_LOI[t] * br + c_LOR[t] * bi;
    hhr += c_HIR[t] * br - c_HII[t] * bi;
    hhi += c_HII[t] * br + c_HIR[t] * bi;
  }

  float* outR = out + (size_t)plane * 2 * HW;
  float* outI = outR + HW;
  const int gi = i0 + i;
  const int gj = j0 + j;
  const int rlo = gi, rhi = (h >> 1) + gi;
  const int clo = gj, chi = (w >> 1) + gj;
  outR[(size_t)rlo * W0 + clo] = llr;
  outI[(size_t)rlo * W0 + clo] = lli;
  outR[(size_t)rlo * W0 + chi] = lhr;
  outI[(size_t)rlo * W0 + chi] = lhi;
  outR[(size_t)rhi * W0 + clo] = hlr;
  outI[(size_t)rhi * W0 + clo] = hli;
  outR[(size_t)rhi * W0 + chi] = hhr;
  outI[(size_t)rhi * W0 + chi] = hhi;

  if (WRITE_LL) {
    const int w2 = w >> 1;
    const int h2 = h >> 1;
    const size_t off = (size_t)plane * h2 * w2 + (size_t)gi * w2 + gj;
    llR[off] = llr;
    llI[off] = lli;
  }
}

extern "C" void kernel_launch(void* const* d_in, const int* in_sizes, int n_in,
                              void* d_out, int out_size, void* d_ws,
                              size_t ws_size, hipStream_t stream) {
  const float* images = (const float*)d_in[0];
  float* out = (float*)d_out;
  constexpr int B = 8, C = 3, H = 1024, W = 1024;
  constexpr int LEVELS = 6;

  // ws layout: ping-pong LL buffers (complex). Level even -> buf0 (512^2 max),
  // level odd -> buf1 (256^2 max). Requirement: ~60 MB of ws.
  float* wsf = (float*)d_ws;
  const size_t S0 = (size_t)B * C * 512 * 512;  // floats
  const size_t S1 = (size_t)B * C * 256 * 256;
  float* buf0R = wsf;
  float* buf0I = wsf + S0;
  float* buf1R = wsf + 2 * S0;
  float* buf1I = wsf + 2 * S0 + S1;

  const float* curR = images;
  const float* curI = nullptr;

  for (int lvl = 0; lvl < LEVELS; ++lvl) {
    const int h = H >> lvl, w = W >> lvl;
    const int tpr = (w / 2) / TJ;
    const int tpc = (h / 2) / TI;
    const int tilesPerPlane = tpr * tpc;
    const int grid = B * C * tilesPerPlane;
    float* llR;
    float* llI;
    if ((lvl & 1) == 0) {
      llR = buf0R;
      llI = buf0I;
    } else {
      llR = buf1R;
      llI = buf1I;
    }
    const bool writeLL = (lvl < LEVELS - 1);

    if (lvl == 0) {
      dwt_level_kernel<false, true><<<grid, 256, 0, stream>>>(
          curR, nullptr, out, llR, llI, h, w, tpr, tilesPerPlane, H * W, W);
    } else if (writeLL) {
      dwt_level_kernel<true, true><<<grid, 256, 0, stream>>>(
          curR, curI, out, llR, llI, h, w, tpr, tilesPerPlane, H * W, W);
    } else {
      dwt_level_kernel<true, false><<<grid, 256, 0, stream>>>(
          curR, curI, out, nullptr, nullptr, h, w, tpr, tilesPerPlane, H * W, W);
    }
    curR = llR;
    curI = llI;
  }
}

// Round 2
// 99.583 us; speedup vs baseline: 2.0965x; 2.0965x over previous
//
#include <hip/hip_runtime.h>

// ---------------------------------------------------------------------------
// Complex Daubechies wavelet pyramid, 6 levels, circular boundary, 6 taps.
// d_out = [B, C, 2, H, W] fp32. Per level: fused column pass -> row pass.
// LL band of levels 0..4 goes ONLY to ws (it is overwritten in d_out by the
// next level anyway); level 5 writes LL to d_out.
// Filters: LO is palindromic, HI antipalindromic -> fold 6 taps to 3.
// ---------------------------------------------------------------------------

#define SQ2 0.7071067811865476

constexpr float kLOR0 = (float)(-0.0662912607 * SQ2);
constexpr float kLOR1 = (float)( 0.1104854346 * SQ2);
constexpr float kLOR2 = (float)( 0.6629126074 * SQ2);
constexpr float kLOI0 = (float)(-0.0855816496 * SQ2);
constexpr float kLOI1 = (float)(-0.0855816496 * SQ2);
constexpr float kLOI2 = (float)( 0.1711632992 * SQ2);
constexpr float kHIR0 = (float)(-0.0662912607 * SQ2);
constexpr float kHIR1 = (float)(-0.1104854346 * SQ2);
constexpr float kHIR2 = (float)( 0.6629126074 * SQ2);
constexpr float kHII0 = (float)( 0.0855816496 * SQ2);
constexpr float kHII1 = (float)(-0.0855816496 * SQ2);
constexpr float kHII2 = (float)(-0.1711632992 * SQ2);

typedef float f2v __attribute__((ext_vector_type(2)));

// 6-tap complex filter pair using (anti)symmetry: xr/xi point at 6 consecutive
// floats. lo uses sums (palindrome), hi uses differences (antipalindrome).
__device__ __forceinline__ void band6(const float* xr, const float* xi,
                                      float& plr, float& pli, float& phr,
                                      float& phi) {
  const float s0 = xr[0] + xr[5], s1 = xr[1] + xr[4], s2 = xr[2] + xr[3];
  const float d0 = xr[0] - xr[5], d1 = xr[1] - xr[4], d2 = xr[2] - xr[3];
  const float t0 = xi[0] + xi[5], t1 = xi[1] + xi[4], t2 = xi[2] + xi[3];
  const float e0 = xi[0] - xi[5], e1 = xi[1] - xi[4], e2 = xi[2] - xi[3];
  plr = (kLOR0 * s0 + kLOR1 * s1 + kLOR2 * s2) -
        (kLOI0 * t0 + kLOI1 * t1 + kLOI2 * t2);
  pli = (kLOI0 * s0 + kLOI1 * s1 + kLOI2 * s2) +
        (kLOR0 * t0 + kLOR1 * t1 + kLOR2 * t2);
  phr = (kHIR0 * d0 + kHIR1 * d1 + kHIR2 * d2) -
        (kHII0 * e0 + kHII1 * e1 + kHII2 * e2);
  phi = (kHII0 * d0 + kHII1 * d1 + kHII2 * d2) +
        (kHIR0 * e0 + kHIR1 * e1 + kHIR2 * e2);
}

// TB: band-tile side (outputs per band per block = TB x TB).
// Input tile: (2TB+4) rows x (2TB+8) floats, staged via global_load_lds f4.
template <int TB, bool HAS_IMAG, bool LL_TO_WS>
__global__ __launch_bounds__(256) void dwt_kernel(
    const float* __restrict__ inR, const float* __restrict__ inI,
    float* __restrict__ out, float* __restrict__ llR, float* __restrict__ llI,
    int h, int w, int tilesPerRow, int tilesPerPlane, int cpx8, int HW,
    int W0) {
  constexpr int RROWS = 2 * TB + 4;           // input rows needed
  constexpr int F4PR = TB / 2 + 2;            // float4 per input row
  constexpr int SW = 4 * F4PR;                // LDS row stride (floats)
  constexpr int NF4 = RROWS * F4PR;
  constexpr int NF4P = ((NF4 + 255) / 256) * 256;
  constexpr int YW = 2 * TB + 5;              // stage-2 stride (odd)
  constexpr int HB = TB / 2;                  // rows per half-pass

  __shared__ float4 s4R[NF4P];
  __shared__ float4 s4I[HAS_IMAG ? NF4P : 1];
  __shared__ float yLR[HB * YW], yLI[HB * YW], yHR[HB * YW], yHI[HB * YW];

  const int tid = threadIdx.x;
  int bid = (int)blockIdx.x;
  bid = (bid & 7) * cpx8 + (bid >> 3);  // XCD-contiguous tile chunks
  const int plane = bid / tilesPerPlane;
  const int trem = bid - plane * tilesPerPlane;
  const int ti = trem / tilesPerRow;
  const int tj = trem - ti * tilesPerRow;

  const int hm = h - 1;
  const int w4 = w >> 2, w4m = w4 - 1;
  const int rowstart = 2 * TB * ti - 3;   // first input row loaded (rel 0)
  const int col4start = HB * tj - 1;      // first float4 col loaded

  const float* pinR = inR + (size_t)plane * h * w;
  const float* pinI = HAS_IMAG ? (inI + (size_t)plane * h * w) : nullptr;

  // ---- stage 1: global -> LDS, width-16 async, linear LDS layout ----
  {
    const int lane = tid & 63;
    const int wid = tid >> 6;
    for (int c0 = wid * 64; c0 < NF4P; c0 += 256) {
      const int idx = c0 + lane;
      const int r = idx / F4PR;
      const int q = idx - r * F4PR;
      const int gr = (rowstart + r) & hm;   // circular wrap (pow2)
      const int gq = (col4start + q) & w4m;
      const size_t goff = (size_t)gr * w4 + gq;
      __builtin_amdgcn_global_load_lds(
          (__attribute__((address_space(1))) void*)((const float4*)pinR + goff),
          (__attribute__((address_space(3))) void*)(&s4R[c0]), 16, 0, 0);
      if (HAS_IMAG) {
        __builtin_amdgcn_global_load_lds(
            (__attribute__((address_space(1))) void*)((const float4*)pinI + goff),
            (__attribute__((address_space(3))) void*)(&s4I[c0]), 16, 0, 0);
      }
    }
  }
  __syncthreads();

  const float* sRf = (const float*)s4R;
  const float* sIf = (const float*)s4I;
  const int i0 = TB * ti, j0g = TB * tj;
  const int h2 = h >> 1, w2 = w >> 1;
  float* outR = out + (size_t)plane * 2 * HW;
  float* outI = outR + HW;

#pragma unroll
  for (int p = 0; p < 2; ++p) {
    // ---- stage 2: column pass for rows [p*HB, p*HB+HB) ----
    for (int idx = tid; idx < HB * YW; idx += 256) {
      const int il = idx / YW;
      const int c = idx - il * YW;
      const int rb = 2 * (p * HB + il);
      const float* col = sRf + rb * SW + c;
      const float x0 = col[0], x1 = col[SW], x2 = col[2 * SW];
      const float x3 = col[3 * SW], x4 = col[4 * SW], x5 = col[5 * SW];
      const float sr0 = x0 + x5, sr1 = x1 + x4, sr2 = x2 + x3;
      const float dr0 = x0 - x5, dr1 = x1 - x4, dr2 = x2 - x3;
      float lr = kLOR0 * sr0 + kLOR1 * sr1 + kLOR2 * sr2;
      float li = kLOI0 * sr0 + kLOI1 * sr1 + kLOI2 * sr2;
      float hr = kHIR0 * dr0 + kHIR1 * dr1 + kHIR2 * dr2;
      float hi = kHII0 * dr0 + kHII1 * dr1 + kHII2 * dr2;
      if (HAS_IMAG) {
        const float* colI = sIf + rb * SW + c;
        const float z0 = colI[0], z1 = colI[SW], z2 = colI[2 * SW];
        const float z3 = colI[3 * SW], z4 = colI[4 * SW], z5 = colI[5 * SW];
        const float si0 = z0 + z5, si1 = z1 + z4, si2 = z2 + z3;
        const float di0 = z0 - z5, di1 = z1 - z4, di2 = z2 - z3;
        lr -= kLOI0 * si0 + kLOI1 * si1 + kLOI2 * si2;
        li += kLOR0 * si0 + kLOR1 * si1 + kLOR2 * si2;
        hr -= kHII0 * di0 + kHII1 * di1 + kHII2 * di2;
        hi += kHIR0 * di0 + kHIR1 * di1 + kHIR2 * di2;
      }
      yLR[idx] = lr;
      yLI[idx] = li;
      yHR[idx] = hr;
      yHI[idx] = hi;
    }
    __syncthreads();

    // ---- stage 3: row pass; thread -> (row il, 2 consecutive cols) ----
    constexpr int NJQ = TB / 2;
    const int jq = tid & (NJQ - 1);
    const int il = tid / NJQ;
    if (il < HB) {
      float o[8][2];
#pragma unroll
      for (int u = 0; u < 2; ++u) {
        const int cb = il * YW + 4 * jq + 2 * u + 1;
        band6(&yLR[cb], &yLI[cb], o[0][u], o[1][u], o[2][u], o[3][u]);
        band6(&yHR[cb], &yHI[cb], o[4][u], o[5][u], o[6][u], o[7][u]);
      }
      const int gi = i0 + p * HB + il;
      const int gj = j0g + 2 * jq;
      const int rlo = gi, rhi = h2 + gi, clo = gj, chi = w2 + gj;
      auto st = [&](float* pdst, int v) {
        f2v t;
        t.x = o[v][0];
        t.y = o[v][1];
        __builtin_nontemporal_store(t, (f2v*)pdst);
      };
      st(outR + (size_t)rlo * W0 + chi, 2);  // LH
      st(outI + (size_t)rlo * W0 + chi, 3);
      st(outR + (size_t)rhi * W0 + clo, 4);  // HL
      st(outI + (size_t)rhi * W0 + clo, 5);
      st(outR + (size_t)rhi * W0 + chi, 6);  // HH
      st(outI + (size_t)rhi * W0 + chi, 7);
      if (LL_TO_WS) {
        const size_t off = (size_t)plane * h2 * w2 + (size_t)gi * w2 + gj;
        f2v a, b;
        a.x = o[0][0];
        a.y = o[0][1];
        b.x = o[1][0];
        b.y = o[1][1];
        *(f2v*)(llR + off) = a;  // cached: next level reads these
        *(f2v*)(llI + off) = b;
      } else {
        st(outR + (size_t)rlo * W0 + clo, 0);  // LL (final level only)
        st(outI + (size_t)rlo * W0 + clo, 1);
      }
    }
    __syncthreads();
  }
}

extern "C" void kernel_launch(void* const* d_in, const int* in_sizes, int n_in,
                              void* d_out, int out_size, void* d_ws,
                              size_t ws_size, hipStream_t stream) {
  const float* images = (const float*)d_in[0];
  float* out = (float*)d_out;
  constexpr int B = 8, C = 3, H = 1024, W = 1024, LEVELS = 6;

  float* wsf = (float*)d_ws;
  const size_t S0 = (size_t)B * C * 512 * 512;
  const size_t S1 = (size_t)B * C * 256 * 256;
  float* buf0R = wsf;
  float* buf0I = wsf + S0;
  float* buf1R = wsf + 2 * S0;
  float* buf1I = wsf + 2 * S0 + S1;

  const float* curR = images;
  const float* curI = nullptr;

  for (int lvl = 0; lvl < LEVELS; ++lvl) {
    const int h = H >> lvl, w = W >> lvl;
    const int TBl = (lvl == 5) ? 16 : 32;
    const int tpr = (w / 2) / TBl;
    const int tpp = tpr * tpr;
    const int grid = B * C * tpp;  // all levels: divisible by 8
    const int cpx8 = grid / 8;
    float* llR = (lvl & 1) ? buf1R : buf0R;
    float* llI = (lvl & 1) ? buf1I : buf0I;

    if (lvl == 0) {
      dwt_kernel<32, false, true><<<grid, 256, 0, stream>>>(
          curR, nullptr, out, llR, llI, h, w, tpr, tpp, cpx8, H * W, W);
    } else if (lvl < LEVELS - 1) {
      dwt_kernel<32, true, true><<<grid, 256, 0, stream>>>(
          curR, curI, out, llR, llI, h, w, tpr, tpp, cpx8, H * W, W);
    } else {
      dwt_kernel<16, true, false><<<grid, 256, 0, stream>>>(
          curR, curI, out, nullptr, nullptr, h, w, tpr, tpp, cpx8, H * W, W);
    }
    curR = llR;
    curI = llI;
  }
}